// Round 4
// baseline (281.458 us; speedup 1.0000x reference)
//
#include <hip/hip_runtime.h>
#include <math.h>

#define EPSF 1e-7f
#define Bsz 2
#define Cch 1024
#define Hh 60
#define Ssz 3600
#define HID 256
#define TDIM 300
#define MH 473

// pool tiling
#define TROWS 15
#define LROWS 21          // TROWS + 6 halo
#define LPITCH 68         // 4-col zero pad both sides of 60 cols
#define CPG 8             // channels per block

// workspace layout (float offsets)
#define OFF_MASK  0            // 2*3600   resized masks
#define OFF_SN2   7200         // 6*3600   sum over c of pooled^2  (atomic -> zeroed)
#define OFF_DOT   28800        // 6*3600   dotmaps                 (atomic -> zeroed)
#define OFF_ACC   50400        // 2*3600   normalized-sim accum    (atomic -> zeroed)
#define OFF_SCORE 57600        // 2*3600   attn scores/probs       (atomic -> zeroed)
#define OFF_WMAP  64800        // 6*3600   pool(inv_sn)
#define OFF_V     86400        // 6*1024   v[c] per (b,kt)
#define OFF_U     92544        // 2*256
#define OFF_KBAR  93056        // 2*256
#define ZERO_OFF  OFF_SN2
#define ZERO_CNT  (OFF_WMAP - OFF_SN2)   // 57600 floats

// ---- load-time side stream + events for graph fork-join concurrency -------
static hipStream_t g_side = nullptr;
static hipEvent_t g_evFork = nullptr, g_evRes = nullptr, g_evJoin = nullptr;
static struct SideInit {
    SideInit() {
        if (hipStreamCreateWithFlags(&g_side, hipStreamNonBlocking) != hipSuccess) g_side = nullptr;
        if (hipEventCreateWithFlags(&g_evFork, hipEventDisableTiming) != hipSuccess) g_evFork = nullptr;
        if (hipEventCreateWithFlags(&g_evRes, hipEventDisableTiming) != hipSuccess) g_evRes = nullptr;
        if (hipEventCreateWithFlags(&g_evJoin, hipEventDisableTiming) != hipSuccess) g_evJoin = nullptr;
    }
} g_sideInit;

// ---------------- mask resize: (473-1)/(60-1) == 8.0 exactly -> subsample --
__global__ void k_resize_mask(const float* __restrict__ masks, float* __restrict__ ws) {
    int idx = blockIdx.x * 256 + threadIdx.x;
    if (idx >= Bsz * Ssz) return;
    int b = idx / Ssz, q = idx - b * Ssz;
    int y = q / Hh, x = q - y * Hh;
    ws[OFF_MASK + idx] = masks[(size_t)b * MH * MH + (size_t)(y * 8) * MH + x * 8];
}

// ---------------- pass A: sn2[b][kt][q] = sum_c pool_kt(supp_c*mask)(q)^2 --
// mask gathered inline (stride-8 subsample); 8 channels/block, reg accum.
__global__ void __launch_bounds__(256) k_pool_sn2(const float* __restrict__ supp,
                                                  const float* __restrict__ masks,
                                                  float* __restrict__ sn2g) {
    __shared__ float mk[LROWS * LPITCH];
    __shared__ float raw[LROWS * LPITCH];
    __shared__ float hs5[LROWS * LPITCH];
    __shared__ float hs7[LROWS * LPITCH];
    int tid = threadIdx.x;
    int tile = blockIdx.x;       // 0..3
    int cg = blockIdx.y;         // 0..127
    int b = blockIdx.z;          // 0..1
    int y0 = tile * TROWS;

    for (int i = tid; i < LROWS * LPITCH; i += 256) {
        mk[i] = 0.f; raw[i] = 0.f; hs5[i] = 0.f; hs7[i] = 0.f;
    }
    __syncthreads();

    int lr[5], lx[5]; bool lv[5], la[5];
    #pragma unroll
    for (int j = 0; j < 5; ++j) {
        int idx = tid + 256 * j;
        int r = idx / 60, x = idx - 60 * r;
        lr[j] = r; lx[j] = x;
        la[j] = idx < 1260;
        int iy = y0 - 3 + r;
        lv[j] = la[j] && (iy >= 0) && (iy < Hh);
    }
    // mask slice: subsample masks at stride 8
    #pragma unroll
    for (int j = 0; j < 5; ++j)
        if (lv[j]) {
            int iy = y0 - 3 + lr[j];
            mk[lr[j] * LPITCH + 4 + lx[j]] =
                masks[(size_t)b * MH * MH + (size_t)(iy * 8) * MH + lx[j] * 8];
        }

    int orow[4], ox[4]; bool ov[4];
    #pragma unroll
    for (int j = 0; j < 4; ++j) {
        int o = tid + 256 * j;
        int oy = o / 60, x = o - 60 * oy;
        orow[j] = oy + 3; ox[j] = x; ov[j] = o < 900;
    }
    float a0[4] = {0,0,0,0}, a1[4] = {0,0,0,0}, a2[4] = {0,0,0,0};

    const float* chbase = supp + ((size_t)b * Cch + (size_t)cg * CPG) * Ssz + (y0 - 3) * 60;
    float pf[5];
    #pragma unroll
    for (int j = 0; j < 5; ++j) pf[j] = lv[j] ? chbase[tid + 256 * j] : 0.f;

    for (int c = 0; c < CPG; ++c) {
        __syncthreads();
        #pragma unroll
        for (int j = 0; j < 5; ++j)
            if (lv[j]) raw[lr[j] * LPITCH + 4 + lx[j]] = pf[j] * mk[lr[j] * LPITCH + 4 + lx[j]];
        __syncthreads();
        #pragma unroll
        for (int j = 0; j < 5; ++j)
            if (la[j]) {
                int base = lr[j] * LPITCH + 4 + lx[j];
                float m3 = raw[base - 3], m2 = raw[base - 2], m1 = raw[base - 1];
                float c0 = raw[base], p1 = raw[base + 1], p2 = raw[base + 2], p3 = raw[base + 3];
                float h5 = m2 + m1 + c0 + p1 + p2;
                hs5[base] = h5;
                hs7[base] = h5 + m3 + p3;
            }
        __syncthreads();
        if (c + 1 < CPG) {
            const float* nb = chbase + (size_t)(c + 1) * Ssz;
            #pragma unroll
            for (int j = 0; j < 5; ++j) pf[j] = lv[j] ? nb[tid + 256 * j] : 0.f;
        }
        #pragma unroll
        for (int j = 0; j < 4; ++j)
            if (ov[j]) {
                int base = orow[j] * LPITCH + 4 + ox[j];
                float p55 = hs5[base - 2*LPITCH] + hs5[base - LPITCH] + hs5[base]
                          + hs5[base + LPITCH] + hs5[base + 2*LPITCH];
                float p71 = raw[base - 3*LPITCH] + raw[base - 2*LPITCH] + raw[base - LPITCH]
                          + raw[base] + raw[base + LPITCH] + raw[base + 2*LPITCH] + raw[base + 3*LPITCH];
                float p17 = hs7[base];
                p55 *= (1.f / 25.f); p71 *= (1.f / 7.f); p17 *= (1.f / 7.f);
                a0[j] += p55 * p55; a1[j] += p71 * p71; a2[j] += p17 * p17;
            }
    }
    float* g0 = sn2g + ((size_t)b * 3 + 0) * Ssz;
    float* g1 = sn2g + ((size_t)b * 3 + 1) * Ssz;
    float* g2 = sn2g + ((size_t)b * 3 + 2) * Ssz;
    #pragma unroll
    for (int j = 0; j < 4; ++j)
        if (ov[j]) {
            int q = (y0 + orow[j] - 3) * 60 + ox[j];
            atomicAdd(&g0[q], a0[j]);
            atomicAdd(&g1[q], a1[j]);
            atomicAdd(&g2[q], a2[j]);
        }
}

// ---------------- wmap[b][kt] = pool_kt(1/sn), row-tiled ------------------
__global__ void k_wmap(const float* __restrict__ sn2g, float* __restrict__ wmapg) {
    __shared__ float inv[LROWS * LPITCH];
    int tile = blockIdx.x;       // 0..3
    int bk = blockIdx.y;         // 0..5 = b*3+kt
    int kt = bk % 3;
    int tid = threadIdx.x;
    int y0 = tile * TROWS;
    for (int i = tid; i < LROWS * LPITCH; i += 256) inv[i] = 0.f;
    __syncthreads();
    const float* sn2 = sn2g + (size_t)bk * Ssz;
    #pragma unroll
    for (int j = 0; j < 5; ++j) {
        int idx = tid + 256 * j;
        if (idx < 1260) {
            int r = idx / 60, x = idx - 60 * r;
            int iy = y0 - 3 + r;
            if (iy >= 0 && iy < Hh)
                inv[r * LPITCH + 4 + x] = 1.0f / sqrtf(fmaxf(sn2[iy * 60 + x], 1e-30f));
        }
    }
    __syncthreads();
    int kh = (kt == 0) ? 5 : (kt == 1) ? 7 : 1;
    int kw = (kt == 0) ? 5 : (kt == 2) ? 7 : 1;
    int rh = kh / 2, rw = kw / 2;
    float norm = 1.f / (float)(kh * kw);
    #pragma unroll
    for (int j = 0; j < 4; ++j) {
        int o = tid + 256 * j;
        if (o < 900) {
            int oy = o / 60, x = o - 60 * oy;
            int base = (oy + 3) * LPITCH + 4 + x;
            float s = 0.f;
            for (int dy = -rh; dy <= rh; ++dy)
                for (int dx = -rw; dx <= rw; ++dx)
                    s += inv[base + dy * LPITCH + dx];
            wmapg[(size_t)bk * Ssz + (y0 + oy) * 60 + x] = s * norm;
        }
    }
}

// ---------------- v[b][kt][c] = sum_p supp*mask*wmap ------------------------
__global__ void k_v(const float* __restrict__ supp, float* __restrict__ ws) {
    int c = blockIdx.x, b = blockIdx.y;
    int tid = threadIdx.x;
    const float* sp = supp + ((size_t)b * Cch + c) * Ssz;
    const float* mrow = ws + OFF_MASK + (size_t)b * Ssz;
    const float* w0 = ws + OFF_WMAP + (size_t)(b * 3 + 0) * Ssz;
    const float* w1 = ws + OFF_WMAP + (size_t)(b * 3 + 1) * Ssz;
    const float* w2 = ws + OFF_WMAP + (size_t)(b * 3 + 2) * Ssz;
    float a0 = 0, a1 = 0, a2 = 0;
    for (int q = tid; q < Ssz; q += 256) {
        float s = sp[q] * mrow[q];
        a0 += s * w0[q]; a1 += s * w1[q]; a2 += s * w2[q];
    }
    __shared__ float red[3][256];
    red[0][tid] = a0; red[1][tid] = a1; red[2][tid] = a2;
    __syncthreads();
    for (int off = 128; off > 0; off >>= 1) {
        if (tid < off) {
            red[0][tid] += red[0][tid + off];
            red[1][tid] += red[1][tid + off];
            red[2][tid] += red[2][tid + off];
        }
        __syncthreads();
    }
    if (tid == 0) {
        ws[OFF_V + (size_t)(b * 3 + 0) * Cch + c] = red[0][0];
        ws[OFF_V + (size_t)(b * 3 + 1) * Cch + c] = red[1][0];
        ws[OFF_V + (size_t)(b * 3 + 2) * Cch + c] = red[2][0];
    }
}

// ---------------- dot[b][kt][q] = sum_c query[c,q]*v[kt][c] -----------------
__global__ void k_dot(const float* __restrict__ query, float* __restrict__ ws) {
    int qt = blockIdx.x, cc = blockIdx.y, b = blockIdx.z;
    int q = qt * 256 + threadIdx.x;
    if (q >= Ssz) return;
    const float* v0 = ws + OFF_V + (size_t)(b * 3 + 0) * Cch;
    const float* v1 = ws + OFF_V + (size_t)(b * 3 + 1) * Cch;
    const float* v2 = ws + OFF_V + (size_t)(b * 3 + 2) * Cch;
    float a0 = 0, a1 = 0, a2 = 0;
    int c0 = cc * 64;
    for (int c = c0; c < c0 + 64; ++c) {
        float qv = query[((size_t)b * Cch + c) * Ssz + q];
        a0 += qv * v0[c]; a1 += qv * v1[c]; a2 += qv * v2[c];
    }
    atomicAdd(&ws[OFF_DOT + (size_t)(b * 3 + 0) * Ssz + q], a0);
    atomicAdd(&ws[OFF_DOT + (size_t)(b * 3 + 1) * Ssz + q], a1);
    atomicAdd(&ws[OFF_DOT + (size_t)(b * 3 + 2) * Ssz + q], a2);
}

// ---------------- sim = pool(dot)/(khkw*S); minmax; accumulate --------------
// padded LDS + separable h-sums: no per-pixel bounds branches
__global__ void k_sim(float* __restrict__ ws) {
    __shared__ float dpad[66 * LPITCH];
    __shared__ float h5p[66 * LPITCH];
    __shared__ float h7p[66 * LPITCH];
    __shared__ float red[256];
    int bk = blockIdx.x; int b = bk / 3; int kt = bk % 3;
    int tid = threadIdx.x;
    const float* dg = ws + OFF_DOT + (size_t)bk * Ssz;
    for (int i = tid; i < 66 * LPITCH; i += 256) {
        int r = i / LPITCH, col = i - r * LPITCH;
        int y = r - 3, x = col - 4;
        dpad[i] = (y >= 0 && y < Hh && x >= 0 && x < Hh) ? dg[y * Hh + x] : 0.f;
    }
    __syncthreads();
    for (int idx = tid; idx < 66 * 60; idx += 256) {
        int r = idx / 60, x = idx - 60 * r;
        int base = r * LPITCH + 4 + x;
        float m3 = dpad[base - 3], m2 = dpad[base - 2], m1 = dpad[base - 1];
        float c0 = dpad[base], p1 = dpad[base + 1], p2 = dpad[base + 2], p3 = dpad[base + 3];
        float h5 = m2 + m1 + c0 + p1 + p2;
        h5p[base] = h5;
        h7p[base] = h5 + m3 + p3;
    }
    __syncthreads();
    float norm = ((kt == 0) ? (1.f / 25.f) : (1.f / 7.f)) * (1.f / (float)Ssz);
    float vals[15];
    float vmin = INFINITY, vmax = -INFINITY;
    #pragma unroll
    for (int j = 0; j < 15; ++j) {
        int q = tid + j * 256;
        if (q < Ssz) {
            int y = q / Hh, x = q - y * Hh;
            int base = (y + 3) * LPITCH + 4 + x;
            float s;
            if (kt == 0)
                s = h5p[base - 2*LPITCH] + h5p[base - LPITCH] + h5p[base]
                  + h5p[base + LPITCH] + h5p[base + 2*LPITCH];
            else if (kt == 1)
                s = dpad[base - 3*LPITCH] + dpad[base - 2*LPITCH] + dpad[base - LPITCH]
                  + dpad[base] + dpad[base + LPITCH] + dpad[base + 2*LPITCH] + dpad[base + 3*LPITCH];
            else
                s = h7p[base];
            float val = s * norm;
            vals[j] = val;
            vmin = fminf(vmin, val); vmax = fmaxf(vmax, val);
        }
    }
    red[tid] = vmin; __syncthreads();
    for (int off = 128; off > 0; off >>= 1) {
        if (tid < off) red[tid] = fminf(red[tid], red[tid + off]);
        __syncthreads();
    }
    float mn = red[0]; __syncthreads();
    red[tid] = vmax; __syncthreads();
    for (int off = 128; off > 0; off >>= 1) {
        if (tid < off) red[tid] = fmaxf(red[tid], red[tid + off]);
        __syncthreads();
    }
    float mx = red[0];
    float inv = 1.f / (mx - mn + EPSF);
    #pragma unroll
    for (int j = 0; j < 15; ++j) {
        int q = tid + j * 256;
        if (q < Ssz) atomicAdd(&ws[OFF_ACC + (size_t)b * Ssz + q], (vals[j] - mn) * inv);
    }
}

// ---------------- corr1 + bilinear downsamples ------------------------------
__global__ void k_final(const float* __restrict__ weight, const float* __restrict__ ws,
                        float* __restrict__ out) {
    int idx = blockIdx.x * 256 + threadIdx.x;
    if (idx < Bsz * Ssz) {
        int b = idx / Ssz, q = idx - b * Ssz;
        out[idx] = weight[b] * (1.f / 3.f) * ws[OFF_ACC + (size_t)b * Ssz + q];
        return;
    }
    int r = idx - Bsz * Ssz;
    int O, outbase;
    if (r < 1800)       { O = 30; outbase = 7200; }
    else if (r < 2250)  { O = 15; outbase = 9000; r -= 1800; }
    else if (r < 2378)  { O = 8;  outbase = 9450; r -= 2250; }
    else return;
    int n = O * O;
    int b = r / n, p = r - b * n;
    int y = p / O, x = p - y * O;
    float sc = (float)(Hh - 1) / (float)(O - 1);
    float py = y * sc, px = x * sc;
    int y0 = (int)floorf(py), x0 = (int)floorf(px);
    int y1 = min(y0 + 1, Hh - 1), x1 = min(x0 + 1, Hh - 1);
    float wy = py - y0, wx = px - x0;
    const float* src = ws + OFF_ACC + (size_t)b * Ssz;
    float v = src[y0 * Hh + x0] * (1.f - wy) * (1.f - wx)
            + src[y1 * Hh + x0] * wy * (1.f - wx)
            + src[y0 * Hh + x1] * (1.f - wy) * wx
            + src[y1 * Hh + x1] * wy * wx;
    out[outbase + r] = v * weight[b] * (1.f / 3.f);
}

// ---------------- APA: u = w_k^T (w_bl^T (w_q^T [text;proto])) --------------
__global__ void __launch_bounds__(1024, 1)
k_apa_u(const float* __restrict__ text, const float* __restrict__ proto,
        const float* __restrict__ w_q, const float* __restrict__ w_bl,
        const float* __restrict__ w_k, float* __restrict__ ws) {
    int b = blockIdx.x;
    int tid = threadIdx.x;
    int lane = tid & 63, w = tid >> 6;        // w = 0..15
    __shared__ float4 p4[16][64];
    __shared__ float qxs[256], qws[256];
    const float4* wq4 = (const float4*)w_q;
    const float4* wbl4 = (const float4*)w_bl;
    const float4* wk4 = (const float4*)w_k;

    float4 acc = {0.f, 0.f, 0.f, 0.f};
    #pragma unroll
    for (int j = 0; j < 35; ++j) {
        int e = w + 16 * j;
        if (e < TDIM + HID) {
            float x = (e < TDIM) ? text[b * TDIM + e] : proto[b * HID + e - TDIM];
            float4 f = wq4[(size_t)e * 64 + lane];
            acc.x += x * f.x; acc.y += x * f.y; acc.z += x * f.z; acc.w += x * f.w;
        }
    }
    p4[w][lane] = acc;
    __syncthreads();
    if (tid < 256) {
        const float* pf = (const float*)p4;
        float s = 0.f;
        #pragma unroll
        for (int ww = 0; ww < 16; ++ww) s += pf[ww * 256 + tid];
        qxs[tid] = s;
    }
    __syncthreads();

    acc.x = acc.y = acc.z = acc.w = 0.f;
    #pragma unroll
    for (int j = 0; j < 16; ++j) {
        int e = w + 16 * j;
        float x = qxs[e];
        float4 f = wbl4[(size_t)e * 64 + lane];
        acc.x += x * f.x; acc.y += x * f.y; acc.z += x * f.z; acc.w += x * f.w;
    }
    p4[w][lane] = acc;
    __syncthreads();
    if (tid < 256) {
        const float* pf = (const float*)p4;
        float s = 0.f;
        #pragma unroll
        for (int ww = 0; ww < 16; ++ww) s += pf[ww * 256 + tid];
        qws[tid] = s;
    }
    __syncthreads();

    acc.x = acc.y = acc.z = acc.w = 0.f;
    #pragma unroll
    for (int j = 0; j < 16; ++j) {
        int e = w + 16 * j;
        float x = qws[e];
        float4 f = wk4[(size_t)e * 64 + lane];
        acc.x += x * f.x; acc.y += x * f.y; acc.z += x * f.z; acc.w += x * f.w;
    }
    p4[w][lane] = acc;
    __syncthreads();
    if (tid < 256) {
        const float* pf = (const float*)p4;
        float s = 0.f;
        #pragma unroll
        for (int ww = 0; ww < 16; ++ww) s += pf[ww * 256 + tid];
        ws[OFF_U + b * HID + tid] = s;
    }
}

// ---------------- score[b,s] = sum_i u[i] * k[b,i,s] ------------------------
__global__ void k_score(const float* __restrict__ kin, float* __restrict__ ws) {
    int st = blockIdx.x, ic = blockIdx.y, b = blockIdx.z;
    int s = st * 256 + threadIdx.x;
    if (s >= Ssz) return;
    const float* u = ws + OFF_U + b * HID;
    float acc = 0.f;
    int i0 = ic * 64;
    for (int i = i0; i < i0 + 64; ++i)
        acc += u[i] * kin[((size_t)b * HID + i) * Ssz + s];
    atomicAdd(&ws[OFF_SCORE + (size_t)b * Ssz + s], acc);
}

// ---------------- softmax over 3600, in place -------------------------------
__global__ void k_softmax(float* __restrict__ ws) {
    int b = blockIdx.x; int tid = threadIdx.x;
    __shared__ float red[256];
    float* sc = ws + OFF_SCORE + (size_t)b * Ssz;
    float vals[15];
    float mx = -INFINITY;
    for (int j = 0; j < 15; ++j) {
        int s = tid + j * 256;
        if (s < Ssz) { vals[j] = sc[s]; mx = fmaxf(mx, vals[j]); }
    }
    red[tid] = mx; __syncthreads();
    for (int off = 128; off > 0; off >>= 1) {
        if (tid < off) red[tid] = fmaxf(red[tid], red[tid + off]);
        __syncthreads();
    }
    mx = red[0]; __syncthreads();
    float sum = 0.f;
    for (int j = 0; j < 15; ++j) {
        int s = tid + j * 256;
        if (s < Ssz) { vals[j] = expf(vals[j] - mx); sum += vals[j]; }
    }
    red[tid] = sum; __syncthreads();
    for (int off = 128; off > 0; off >>= 1) {
        if (tid < off) red[tid] += red[tid + off];
        __syncthreads();
    }
    float inv = 1.f / red[0];
    for (int j = 0; j < 15; ++j) {
        int s = tid + j * 256;
        if (s < Ssz) sc[s] = vals[j] * inv;
    }
}

// ---------------- kbar[b,i] = sum_s p[s]*k[b,i,s] ---------------------------
__global__ void k_kbar(const float* __restrict__ kin, float* __restrict__ ws) {
    int i = blockIdx.x, b = blockIdx.y;
    int tid = threadIdx.x;
    const float* p = ws + OFF_SCORE + (size_t)b * Ssz;
    const float* kr = kin + ((size_t)b * HID + i) * Ssz;
    float acc = 0.f;
    for (int s = tid; s < Ssz; s += 256) acc += p[s] * kr[s];
    __shared__ float red[256];
    red[tid] = acc; __syncthreads();
    for (int off = 128; off > 0; off >>= 1) {
        if (tid < off) red[tid] += red[tid + off];
        __syncthreads();
    }
    if (tid == 0) ws[OFF_KBAR + b * HID + i] = red[0];
}

// ---------------- out = w_proj^T (w_k kbar) + b + proto ---------------------
__global__ void __launch_bounds__(1024, 1)
k_apa_out(const float* __restrict__ w_k, const float* __restrict__ w_proj,
          const float* __restrict__ b_proj, const float* __restrict__ proto,
          const float* __restrict__ ws, float* __restrict__ out) {
    int b = blockIdx.x;
    int tid = threadIdx.x;
    int lane = tid & 63, w = tid >> 6;
    __shared__ float4 kbs[64];
    __shared__ float o1s[256];
    __shared__ float4 p4[16][64];
    const float4* wk4 = (const float4*)w_k;
    const float4* wp4 = (const float4*)w_proj;

    if (tid < 64) kbs[tid] = ((const float4*)(ws + OFF_KBAR + b * HID))[tid];
    __syncthreads();

    float4 kb4 = kbs[lane];
    #pragma unroll
    for (int r = 0; r < 16; ++r) {
        int h = w + 16 * r;
        float4 f = wk4[(size_t)h * 64 + lane];
        float p = f.x * kb4.x + f.y * kb4.y + f.z * kb4.z + f.w * kb4.w;
        #pragma unroll
        for (int m = 32; m >= 1; m >>= 1) p += __shfl_xor(p, m, 64);
        if (lane == 0) o1s[h] = p;
    }
    __syncthreads();

    float4 acc = {0.f, 0.f, 0.f, 0.f};
    #pragma unroll
    for (int j = 0; j < 16; ++j) {
        int d = w + 16 * j;
        float x = o1s[d];
        float4 f = wp4[(size_t)d * 64 + lane];
        acc.x += x * f.x; acc.y += x * f.y; acc.z += x * f.z; acc.w += x * f.w;
    }
    p4[w][lane] = acc;
    __syncthreads();
    if (tid < 256) {
        const float* pf = (const float*)p4;
        float s = 0.f;
        #pragma unroll
        for (int ww = 0; ww < 16; ++ww) s += pf[ww * 256 + tid];
        out[9578 + b * HID + tid] = s + b_proj[tid] + proto[b * HID + tid];
    }
}

extern "C" void kernel_launch(void* const* d_in, const int* in_sizes, int n_in,
                              void* d_out, int out_size, void* d_ws, size_t ws_size,
                              hipStream_t stream) {
    const float* weight = (const float*)d_in[0];
    const float* query  = (const float*)d_in[1];
    const float* supp   = (const float*)d_in[2];
    const float* masks  = (const float*)d_in[3];
    const float* kin    = (const float*)d_in[4];
    const float* text   = (const float*)d_in[5];
    const float* proto  = (const float*)d_in[6];
    const float* w_q    = (const float*)d_in[7];
    const float* w_k    = (const float*)d_in[8];
    const float* w_bl   = (const float*)d_in[9];
    const float* w_proj = (const float*)d_in[10];
    const float* b_proj = (const float*)d_in[11];
    float* out = (float*)d_out;
    float* ws  = (float*)d_ws;

    const bool fork = (g_side && g_evFork && g_evRes && g_evJoin);
    hipStream_t s2 = fork ? g_side : stream;

    // zero atomic-accumulated regions (ws is poisoned 0xAA before every call)
    hipMemsetAsync(ws + ZERO_OFF, 0, (size_t)ZERO_CNT * sizeof(float), stream);
    if (fork) {
        hipEventRecord(g_evFork, stream);
        hipStreamWaitEvent(s2, g_evFork, 0);
    }

    // ---- side chain: mask resize (feeds k_v) + full APA pipeline ----
    k_resize_mask<<<(Bsz * Ssz + 255) / 256, 256, 0, s2>>>(masks, ws);
    if (fork) hipEventRecord(g_evRes, s2);
    k_apa_u<<<Bsz, 1024, 0, s2>>>(text, proto, w_q, w_bl, w_k, ws);
    k_score<<<dim3(15, 4, Bsz), 256, 0, s2>>>(kin, ws);
    k_softmax<<<Bsz, 256, 0, s2>>>(ws);
    k_kbar<<<dim3(HID, Bsz), 256, 0, s2>>>(kin, ws);
    k_apa_out<<<Bsz, 1024, 0, s2>>>(w_k, w_proj, b_proj, proto, ws, out);
    if (fork) hipEventRecord(g_evJoin, s2);

    // ---- main chain: SPM ----
    k_pool_sn2<<<dim3(4, Cch / CPG, Bsz), 256, 0, stream>>>(supp, masks, ws + OFF_SN2);
    k_wmap<<<dim3(4, 6), 256, 0, stream>>>(ws + OFF_SN2, ws + OFF_WMAP);
    if (fork) hipStreamWaitEvent(stream, g_evRes, 0);
    k_v<<<dim3(Cch, Bsz), 256, 0, stream>>>(supp, ws);
    k_dot<<<dim3(15, Cch / 64, Bsz), 256, 0, stream>>>(query, ws);
    k_sim<<<6, 256, 0, stream>>>(ws);
    k_final<<<(Bsz * Ssz + 2378 + 255) / 256, 256, 0, stream>>>(weight, ws, out);

    if (fork) hipStreamWaitEvent(stream, g_evJoin, 0);
}

// Round 5
// 232.092 us; speedup vs baseline: 1.2127x; 1.2127x over previous
//
#include <hip/hip_runtime.h>
#include <math.h>

#define EPSF 1e-7f
#define Bsz 2
#define Cch 1024
#define Hh 60
#define Ssz 3600
#define HID 256
#define TDIM 300
#define MH 473

// pool tiling
#define TROWS 15
#define LROWS 21          // TROWS + 6 halo
#define LPITCH 68         // 4-col zero pad both sides of 60 cols
#define CPG 8             // channels per block (processed as 4 float2 pairs)

// workspace layout (float offsets)
#define OFF_SN2   7200         // 6*3600   sum over c of pooled^2  (atomic -> zeroed)
#define OFF_DOT   28800        // 6*3600   dotmaps                 (atomic -> zeroed)
#define OFF_ACC   50400        // 2*3600   normalized-sim accum    (atomic -> zeroed)
#define OFF_SCORE 57600        // 2*3600   attn scores/probs       (atomic -> zeroed)
#define OFF_WMAP  64800        // 6*3600   pool(inv_sn)
#define OFF_V     86400        // 6*1024   v[c] per (b,kt)
#define OFF_U     92544        // 2*256
#define OFF_KBAR  93056        // 2*256
#define ZERO_OFF  OFF_SN2
#define ZERO_CNT  (OFF_WMAP - OFF_SN2)   // 57600 floats

// ---------------- pass A: sn2[b][kt][q] = sum_c pool_kt(supp_c*mask)(q)^2 --
// mask gathered inline (stride-8 subsample of 473x473 == exact bilinear).
// channel PAIRS staged through LDS as float2 (b64 LDS ops, half the count).
__global__ void __launch_bounds__(256) k_pool_sn2(const float* __restrict__ supp,
                                                  const float* __restrict__ masks,
                                                  float* __restrict__ sn2g) {
    __shared__ float  mk[LROWS * LPITCH];
    __shared__ float2 raw[LROWS * LPITCH];
    __shared__ float2 h5s[LROWS * LPITCH];
    __shared__ float2 h7s[LROWS * LPITCH];
    int tid = threadIdx.x;
    int tile = blockIdx.x;       // 0..3
    int cg = blockIdx.y;         // 0..127
    int b = blockIdx.z;          // 0..1
    int y0 = tile * TROWS;

    const float2 z2 = {0.f, 0.f};
    for (int i = tid; i < LROWS * LPITCH; i += 256) {
        mk[i] = 0.f; raw[i] = z2; h5s[i] = z2; h7s[i] = z2;
    }
    __syncthreads();

    int lr[5], lx[5]; bool lv[5], la[5];
    #pragma unroll
    for (int j = 0; j < 5; ++j) {
        int idx = tid + 256 * j;
        int r = idx / 60, x = idx - 60 * r;
        lr[j] = r; lx[j] = x;
        la[j] = idx < 1260;
        int iy = y0 - 3 + r;
        lv[j] = la[j] && (iy >= 0) && (iy < Hh);
    }
    // mask slice: stride-8 subsample
    #pragma unroll
    for (int j = 0; j < 5; ++j)
        if (lv[j]) {
            int iy = y0 - 3 + lr[j];
            mk[lr[j] * LPITCH + 4 + lx[j]] =
                masks[(size_t)b * MH * MH + (size_t)(iy * 8) * MH + lx[j] * 8];
        }

    int orow[4], ox[4]; bool ov[4];
    #pragma unroll
    for (int j = 0; j < 4; ++j) {
        int o = tid + 256 * j;
        int oy = o / 60, x = o - 60 * oy;
        orow[j] = oy + 3; ox[j] = x; ov[j] = o < 900;
    }
    float a0[4] = {0,0,0,0}, a1[4] = {0,0,0,0}, a2[4] = {0,0,0,0};

    const float* chbase = supp + ((size_t)b * Cch + (size_t)cg * CPG) * Ssz + (y0 - 3) * 60;
    float pf0[5], pf1[5];
    #pragma unroll
    for (int j = 0; j < 5; ++j) {
        pf0[j] = lv[j] ? chbase[tid + 256 * j] : 0.f;
        pf1[j] = lv[j] ? chbase[Ssz + tid + 256 * j] : 0.f;
    }

    for (int p = 0; p < CPG / 2; ++p) {
        __syncthreads();
        #pragma unroll
        for (int j = 0; j < 5; ++j)
            if (lv[j]) {
                float m = mk[lr[j] * LPITCH + 4 + lx[j]];
                raw[lr[j] * LPITCH + 4 + lx[j]] = make_float2(pf0[j] * m, pf1[j] * m);
            }
        __syncthreads();
        // horizontal sums (float2 = 2 channels at once)
        #pragma unroll
        for (int j = 0; j < 5; ++j)
            if (la[j]) {
                int base = lr[j] * LPITCH + 4 + lx[j];
                float2 m3 = raw[base - 3], m2 = raw[base - 2], m1 = raw[base - 1];
                float2 c0 = raw[base], p1 = raw[base + 1], p2 = raw[base + 2], p3 = raw[base + 3];
                float2 h5, h7;
                h5.x = m2.x + m1.x + c0.x + p1.x + p2.x;
                h5.y = m2.y + m1.y + c0.y + p1.y + p2.y;
                h7.x = h5.x + m3.x + p3.x;
                h7.y = h5.y + m3.y + p3.y;
                h5s[base] = h5; h7s[base] = h7;
            }
        __syncthreads();
        // prefetch next pair
        if (p + 1 < CPG / 2) {
            const float* nb = chbase + (size_t)(2 * p + 2) * Ssz;
            #pragma unroll
            for (int j = 0; j < 5; ++j) {
                pf0[j] = lv[j] ? nb[tid + 256 * j] : 0.f;
                pf1[j] = lv[j] ? nb[Ssz + tid + 256 * j] : 0.f;
            }
        }
        // vertical sums + square + register accumulate (both channels)
        #pragma unroll
        for (int j = 0; j < 4; ++j)
            if (ov[j]) {
                int base = orow[j] * LPITCH + 4 + ox[j];
                float2 sa = h5s[base - 2*LPITCH], sb = h5s[base - LPITCH], sc0 = h5s[base];
                float2 sd = h5s[base + LPITCH], se = h5s[base + 2*LPITCH];
                float p55x = (sa.x + sb.x + sc0.x + sd.x + se.x) * (1.f / 25.f);
                float p55y = (sa.y + sb.y + sc0.y + sd.y + se.y) * (1.f / 25.f);
                float2 ra = raw[base - 3*LPITCH], rb = raw[base - 2*LPITCH], rc = raw[base - LPITCH];
                float2 rd = raw[base], re = raw[base + LPITCH], rf = raw[base + 2*LPITCH], rg = raw[base + 3*LPITCH];
                float p71x = (ra.x + rb.x + rc.x + rd.x + re.x + rf.x + rg.x) * (1.f / 7.f);
                float p71y = (ra.y + rb.y + rc.y + rd.y + re.y + rf.y + rg.y) * (1.f / 7.f);
                float2 h7v = h7s[base];
                float p17x = h7v.x * (1.f / 7.f), p17y = h7v.y * (1.f / 7.f);
                a0[j] += p55x * p55x + p55y * p55y;
                a1[j] += p71x * p71x + p71y * p71y;
                a2[j] += p17x * p17x + p17y * p17y;
            }
    }
    float* g0 = sn2g + ((size_t)b * 3 + 0) * Ssz;
    float* g1 = sn2g + ((size_t)b * 3 + 1) * Ssz;
    float* g2 = sn2g + ((size_t)b * 3 + 2) * Ssz;
    #pragma unroll
    for (int j = 0; j < 4; ++j)
        if (ov[j]) {
            int q = (y0 + orow[j] - 3) * 60 + ox[j];
            atomicAdd(&g0[q], a0[j]);
            atomicAdd(&g1[q], a1[j]);
            atomicAdd(&g2[q], a2[j]);
        }
}

// ---------------- wmap[b][kt] = pool_kt(1/sn), row-tiled ------------------
__global__ void k_wmap(const float* __restrict__ sn2g, float* __restrict__ wmapg) {
    __shared__ float inv[LROWS * LPITCH];
    int tile = blockIdx.x;       // 0..3
    int bk = blockIdx.y;         // 0..5 = b*3+kt
    int kt = bk % 3;
    int tid = threadIdx.x;
    int y0 = tile * TROWS;
    for (int i = tid; i < LROWS * LPITCH; i += 256) inv[i] = 0.f;
    __syncthreads();
    const float* sn2 = sn2g + (size_t)bk * Ssz;
    #pragma unroll
    for (int j = 0; j < 5; ++j) {
        int idx = tid + 256 * j;
        if (idx < 1260) {
            int r = idx / 60, x = idx - 60 * r;
            int iy = y0 - 3 + r;
            if (iy >= 0 && iy < Hh)
                inv[r * LPITCH + 4 + x] = 1.0f / sqrtf(fmaxf(sn2[iy * 60 + x], 1e-30f));
        }
    }
    __syncthreads();
    int kh = (kt == 0) ? 5 : (kt == 1) ? 7 : 1;
    int kw = (kt == 0) ? 5 : (kt == 2) ? 7 : 1;
    int rh = kh / 2, rw = kw / 2;
    float norm = 1.f / (float)(kh * kw);
    #pragma unroll
    for (int j = 0; j < 4; ++j) {
        int o = tid + 256 * j;
        if (o < 900) {
            int oy = o / 60, x = o - 60 * oy;
            int base = (oy + 3) * LPITCH + 4 + x;
            float s = 0.f;
            for (int dy = -rh; dy <= rh; ++dy)
                for (int dx = -rw; dx <= rw; ++dx)
                    s += inv[base + dy * LPITCH + dx];
            wmapg[(size_t)bk * Ssz + (y0 + oy) * 60 + x] = s * norm;
        }
    }
}

// ---------------- v[b][kt][c] = sum_p supp*mask*wmap (mask inline) ----------
__global__ void k_v(const float* __restrict__ supp, const float* __restrict__ masks,
                    float* __restrict__ ws) {
    int c = blockIdx.x, b = blockIdx.y;
    int tid = threadIdx.x;
    const float* sp = supp + ((size_t)b * Cch + c) * Ssz;
    const float* mbase = masks + (size_t)b * MH * MH;
    const float* w0 = ws + OFF_WMAP + (size_t)(b * 3 + 0) * Ssz;
    const float* w1 = ws + OFF_WMAP + (size_t)(b * 3 + 1) * Ssz;
    const float* w2 = ws + OFF_WMAP + (size_t)(b * 3 + 2) * Ssz;
    float a0 = 0, a1 = 0, a2 = 0;
    for (int q = tid; q < Ssz; q += 256) {
        int y = q / Hh, x = q - y * Hh;
        float s = sp[q] * mbase[(size_t)(y * 8) * MH + x * 8];
        a0 += s * w0[q]; a1 += s * w1[q]; a2 += s * w2[q];
    }
    __shared__ float red[3][256];
    red[0][tid] = a0; red[1][tid] = a1; red[2][tid] = a2;
    __syncthreads();
    for (int off = 128; off > 0; off >>= 1) {
        if (tid < off) {
            red[0][tid] += red[0][tid + off];
            red[1][tid] += red[1][tid + off];
            red[2][tid] += red[2][tid + off];
        }
        __syncthreads();
    }
    if (tid == 0) {
        ws[OFF_V + (size_t)(b * 3 + 0) * Cch + c] = red[0][0];
        ws[OFF_V + (size_t)(b * 3 + 1) * Cch + c] = red[1][0];
        ws[OFF_V + (size_t)(b * 3 + 2) * Cch + c] = red[2][0];
    }
}

// ---------------- dot[b][kt][q] = sum_c query[c,q]*v[kt][c] -----------------
__global__ void k_dot(const float* __restrict__ query, float* __restrict__ ws) {
    int qt = blockIdx.x, cc = blockIdx.y, b = blockIdx.z;
    int q = qt * 256 + threadIdx.x;
    if (q >= Ssz) return;
    const float* v0 = ws + OFF_V + (size_t)(b * 3 + 0) * Cch;
    const float* v1 = ws + OFF_V + (size_t)(b * 3 + 1) * Cch;
    const float* v2 = ws + OFF_V + (size_t)(b * 3 + 2) * Cch;
    float a0 = 0, a1 = 0, a2 = 0;
    int c0 = cc * 64;
    for (int c = c0; c < c0 + 64; ++c) {
        float qv = query[((size_t)b * Cch + c) * Ssz + q];
        a0 += qv * v0[c]; a1 += qv * v1[c]; a2 += qv * v2[c];
    }
    atomicAdd(&ws[OFF_DOT + (size_t)(b * 3 + 0) * Ssz + q], a0);
    atomicAdd(&ws[OFF_DOT + (size_t)(b * 3 + 1) * Ssz + q], a1);
    atomicAdd(&ws[OFF_DOT + (size_t)(b * 3 + 2) * Ssz + q], a2);
}

// ---------------- sim = pool(dot)/(khkw*S); minmax; accumulate --------------
__global__ void k_sim(float* __restrict__ ws) {
    __shared__ float dpad[66 * LPITCH];
    __shared__ float h5p[66 * LPITCH];
    __shared__ float h7p[66 * LPITCH];
    __shared__ float red[256];
    int bk = blockIdx.x; int b = bk / 3; int kt = bk % 3;
    int tid = threadIdx.x;
    const float* dg = ws + OFF_DOT + (size_t)bk * Ssz;
    for (int i = tid; i < 66 * LPITCH; i += 256) {
        int r = i / LPITCH, col = i - r * LPITCH;
        int y = r - 3, x = col - 4;
        dpad[i] = (y >= 0 && y < Hh && x >= 0 && x < Hh) ? dg[y * Hh + x] : 0.f;
    }
    __syncthreads();
    for (int idx = tid; idx < 66 * 60; idx += 256) {
        int r = idx / 60, x = idx - 60 * r;
        int base = r * LPITCH + 4 + x;
        float m3 = dpad[base - 3], m2 = dpad[base - 2], m1 = dpad[base - 1];
        float c0 = dpad[base], p1 = dpad[base + 1], p2 = dpad[base + 2], p3 = dpad[base + 3];
        float h5 = m2 + m1 + c0 + p1 + p2;
        h5p[base] = h5;
        h7p[base] = h5 + m3 + p3;
    }
    __syncthreads();
    float norm = ((kt == 0) ? (1.f / 25.f) : (1.f / 7.f)) * (1.f / (float)Ssz);
    float vals[15];
    float vmin = INFINITY, vmax = -INFINITY;
    #pragma unroll
    for (int j = 0; j < 15; ++j) {
        int q = tid + j * 256;
        if (q < Ssz) {
            int y = q / Hh, x = q - y * Hh;
            int base = (y + 3) * LPITCH + 4 + x;
            float s;
            if (kt == 0)
                s = h5p[base - 2*LPITCH] + h5p[base - LPITCH] + h5p[base]
                  + h5p[base + LPITCH] + h5p[base + 2*LPITCH];
            else if (kt == 1)
                s = dpad[base - 3*LPITCH] + dpad[base - 2*LPITCH] + dpad[base - LPITCH]
                  + dpad[base] + dpad[base + LPITCH] + dpad[base + 2*LPITCH] + dpad[base + 3*LPITCH];
            else
                s = h7p[base];
            float val = s * norm;
            vals[j] = val;
            vmin = fminf(vmin, val); vmax = fmaxf(vmax, val);
        }
    }
    red[tid] = vmin; __syncthreads();
    for (int off = 128; off > 0; off >>= 1) {
        if (tid < off) red[tid] = fminf(red[tid], red[tid + off]);
        __syncthreads();
    }
    float mn = red[0]; __syncthreads();
    red[tid] = vmax; __syncthreads();
    for (int off = 128; off > 0; off >>= 1) {
        if (tid < off) red[tid] = fmaxf(red[tid], red[tid + off]);
        __syncthreads();
    }
    float mx = red[0];
    float inv = 1.f / (mx - mn + EPSF);
    #pragma unroll
    for (int j = 0; j < 15; ++j) {
        int q = tid + j * 256;
        if (q < Ssz) atomicAdd(&ws[OFF_ACC + (size_t)b * Ssz + q], (vals[j] - mn) * inv);
    }
}

// ---------------- corr1 + bilinear downsamples ------------------------------
__global__ void k_final(const float* __restrict__ weight, const float* __restrict__ ws,
                        float* __restrict__ out) {
    int idx = blockIdx.x * 256 + threadIdx.x;
    if (idx < Bsz * Ssz) {
        int b = idx / Ssz, q = idx - b * Ssz;
        out[idx] = weight[b] * (1.f / 3.f) * ws[OFF_ACC + (size_t)b * Ssz + q];
        return;
    }
    int r = idx - Bsz * Ssz;
    int O, outbase;
    if (r < 1800)       { O = 30; outbase = 7200; }
    else if (r < 2250)  { O = 15; outbase = 9000; r -= 1800; }
    else if (r < 2378)  { O = 8;  outbase = 9450; r -= 2250; }
    else return;
    int n = O * O;
    int b = r / n, p = r - b * n;
    int y = p / O, x = p - y * O;
    float sc = (float)(Hh - 1) / (float)(O - 1);
    float py = y * sc, px = x * sc;
    int y0 = (int)floorf(py), x0 = (int)floorf(px);
    int y1 = min(y0 + 1, Hh - 1), x1 = min(x0 + 1, Hh - 1);
    float wy = py - y0, wx = px - x0;
    const float* src = ws + OFF_ACC + (size_t)b * Ssz;
    float v = src[y0 * Hh + x0] * (1.f - wy) * (1.f - wx)
            + src[y1 * Hh + x0] * wy * (1.f - wx)
            + src[y0 * Hh + x1] * (1.f - wy) * wx
            + src[y1 * Hh + x1] * wy * wx;
    out[outbase + r] = v * weight[b] * (1.f / 3.f);
}

// ---------------- APA: u = w_k^T (w_bl^T (w_q^T [text;proto])) --------------
__global__ void __launch_bounds__(1024, 1)
k_apa_u(const float* __restrict__ text, const float* __restrict__ proto,
        const float* __restrict__ w_q, const float* __restrict__ w_bl,
        const float* __restrict__ w_k, float* __restrict__ ws) {
    int b = blockIdx.x;
    int tid = threadIdx.x;
    int lane = tid & 63, w = tid >> 6;        // w = 0..15
    __shared__ float4 p4[16][64];
    __shared__ float qxs[256], qws[256];
    const float4* wq4 = (const float4*)w_q;
    const float4* wbl4 = (const float4*)w_bl;
    const float4* wk4 = (const float4*)w_k;

    float4 acc = {0.f, 0.f, 0.f, 0.f};
    #pragma unroll
    for (int j = 0; j < 35; ++j) {
        int e = w + 16 * j;
        if (e < TDIM + HID) {
            float x = (e < TDIM) ? text[b * TDIM + e] : proto[b * HID + e - TDIM];
            float4 f = wq4[(size_t)e * 64 + lane];
            acc.x += x * f.x; acc.y += x * f.y; acc.z += x * f.z; acc.w += x * f.w;
        }
    }
    p4[w][lane] = acc;
    __syncthreads();
    if (tid < 256) {
        const float* pf = (const float*)p4;
        float s = 0.f;
        #pragma unroll
        for (int ww = 0; ww < 16; ++ww) s += pf[ww * 256 + tid];
        qxs[tid] = s;
    }
    __syncthreads();

    acc.x = acc.y = acc.z = acc.w = 0.f;
    #pragma unroll
    for (int j = 0; j < 16; ++j) {
        int e = w + 16 * j;
        float x = qxs[e];
        float4 f = wbl4[(size_t)e * 64 + lane];
        acc.x += x * f.x; acc.y += x * f.y; acc.z += x * f.z; acc.w += x * f.w;
    }
    p4[w][lane] = acc;
    __syncthreads();
    if (tid < 256) {
        const float* pf = (const float*)p4;
        float s = 0.f;
        #pragma unroll
        for (int ww = 0; ww < 16; ++ww) s += pf[ww * 256 + tid];
        qws[tid] = s;
    }
    __syncthreads();

    acc.x = acc.y = acc.z = acc.w = 0.f;
    #pragma unroll
    for (int j = 0; j < 16; ++j) {
        int e = w + 16 * j;
        float x = qws[e];
        float4 f = wk4[(size_t)e * 64 + lane];
        acc.x += x * f.x; acc.y += x * f.y; acc.z += x * f.z; acc.w += x * f.w;
    }
    p4[w][lane] = acc;
    __syncthreads();
    if (tid < 256) {
        const float* pf = (const float*)p4;
        float s = 0.f;
        #pragma unroll
        for (int ww = 0; ww < 16; ++ww) s += pf[ww * 256 + tid];
        ws[OFF_U + b * HID + tid] = s;
    }
}

// ---------------- score[b,s] = sum_i u[i] * k[b,i,s] ------------------------
__global__ void k_score(const float* __restrict__ kin, float* __restrict__ ws) {
    int st = blockIdx.x, ic = blockIdx.y, b = blockIdx.z;
    int s = st * 256 + threadIdx.x;
    if (s >= Ssz) return;
    const float* u = ws + OFF_U + b * HID;
    float acc = 0.f;
    int i0 = ic * 64;
    for (int i = i0; i < i0 + 64; ++i)
        acc += u[i] * kin[((size_t)b * HID + i) * Ssz + s];
    atomicAdd(&ws[OFF_SCORE + (size_t)b * Ssz + s], acc);
}

// ---------------- softmax over 3600, in place -------------------------------
__global__ void k_softmax(float* __restrict__ ws) {
    int b = blockIdx.x; int tid = threadIdx.x;
    __shared__ float red[256];
    float* sc = ws + OFF_SCORE + (size_t)b * Ssz;
    float vals[15];
    float mx = -INFINITY;
    for (int j = 0; j < 15; ++j) {
        int s = tid + j * 256;
        if (s < Ssz) { vals[j] = sc[s]; mx = fmaxf(mx, vals[j]); }
    }
    red[tid] = mx; __syncthreads();
    for (int off = 128; off > 0; off >>= 1) {
        if (tid < off) red[tid] = fmaxf(red[tid], red[tid + off]);
        __syncthreads();
    }
    mx = red[0]; __syncthreads();
    float sum = 0.f;
    for (int j = 0; j < 15; ++j) {
        int s = tid + j * 256;
        if (s < Ssz) { vals[j] = expf(vals[j] - mx); sum += vals[j]; }
    }
    red[tid] = sum; __syncthreads();
    for (int off = 128; off > 0; off >>= 1) {
        if (tid < off) red[tid] += red[tid + off];
        __syncthreads();
    }
    float inv = 1.f / red[0];
    for (int j = 0; j < 15; ++j) {
        int s = tid + j * 256;
        if (s < Ssz) sc[s] = vals[j] * inv;
    }
}

// ---------------- kbar[b,i] = sum_s p[s]*k[b,i,s] ---------------------------
__global__ void k_kbar(const float* __restrict__ kin, float* __restrict__ ws) {
    int i = blockIdx.x, b = blockIdx.y;
    int tid = threadIdx.x;
    const float* p = ws + OFF_SCORE + (size_t)b * Ssz;
    const float* kr = kin + ((size_t)b * HID + i) * Ssz;
    float acc = 0.f;
    for (int s = tid; s < Ssz; s += 256) acc += p[s] * kr[s];
    __shared__ float red[256];
    red[tid] = acc; __syncthreads();
    for (int off = 128; off > 0; off >>= 1) {
        if (tid < off) red[tid] += red[tid + off];
        __syncthreads();
    }
    if (tid == 0) ws[OFF_KBAR + b * HID + i] = red[0];
}

// ---------------- out = w_proj^T (w_k kbar) + b + proto ---------------------
__global__ void __launch_bounds__(1024, 1)
k_apa_out(const float* __restrict__ w_k, const float* __restrict__ w_proj,
          const float* __restrict__ b_proj, const float* __restrict__ proto,
          const float* __restrict__ ws, float* __restrict__ out) {
    int b = blockIdx.x;
    int tid = threadIdx.x;
    int lane = tid & 63, w = tid >> 6;
    __shared__ float4 kbs[64];
    __shared__ float o1s[256];
    __shared__ float4 p4[16][64];
    const float4* wk4 = (const float4*)w_k;
    const float4* wp4 = (const float4*)w_proj;

    if (tid < 64) kbs[tid] = ((const float4*)(ws + OFF_KBAR + b * HID))[tid];
    __syncthreads();

    float4 kb4 = kbs[lane];
    #pragma unroll
    for (int r = 0; r < 16; ++r) {
        int h = w + 16 * r;
        float4 f = wk4[(size_t)h * 64 + lane];
        float p = f.x * kb4.x + f.y * kb4.y + f.z * kb4.z + f.w * kb4.w;
        #pragma unroll
        for (int m = 32; m >= 1; m >>= 1) p += __shfl_xor(p, m, 64);
        if (lane == 0) o1s[h] = p;
    }
    __syncthreads();

    float4 acc = {0.f, 0.f, 0.f, 0.f};
    #pragma unroll
    for (int j = 0; j < 16; ++j) {
        int d = w + 16 * j;
        float x = o1s[d];
        float4 f = wp4[(size_t)d * 64 + lane];
        acc.x += x * f.x; acc.y += x * f.y; acc.z += x * f.z; acc.w += x * f.w;
    }
    p4[w][lane] = acc;
    __syncthreads();
    if (tid < 256) {
        const float* pf = (const float*)p4;
        float s = 0.f;
        #pragma unroll
        for (int ww = 0; ww < 16; ++ww) s += pf[ww * 256 + tid];
        out[9578 + b * HID + tid] = s + b_proj[tid] + proto[b * HID + tid];
    }
}

extern "C" void kernel_launch(void* const* d_in, const int* in_sizes, int n_in,
                              void* d_out, int out_size, void* d_ws, size_t ws_size,
                              hipStream_t stream) {
    const float* weight = (const float*)d_in[0];
    const float* query  = (const float*)d_in[1];
    const float* supp   = (const float*)d_in[2];
    const float* masks  = (const float*)d_in[3];
    const float* kin    = (const float*)d_in[4];
    const float* text   = (const float*)d_in[5];
    const float* proto  = (const float*)d_in[6];
    const float* w_q    = (const float*)d_in[7];
    const float* w_k    = (const float*)d_in[8];
    const float* w_bl   = (const float*)d_in[9];
    const float* w_proj = (const float*)d_in[10];
    const float* b_proj = (const float*)d_in[11];
    float* out = (float*)d_out;
    float* ws  = (float*)d_ws;

    // zero atomic-accumulated regions (ws is poisoned 0xAA before every call)
    hipMemsetAsync(ws + ZERO_OFF, 0, (size_t)ZERO_CNT * sizeof(float), stream);

    // ---- SPM ----
    k_pool_sn2<<<dim3(4, Cch / CPG, Bsz), 256, 0, stream>>>(supp, masks, ws + OFF_SN2);
    k_wmap<<<dim3(4, 6), 256, 0, stream>>>(ws + OFF_SN2, ws + OFF_WMAP);
    k_v<<<dim3(Cch, Bsz), 256, 0, stream>>>(supp, masks, ws);
    k_dot<<<dim3(15, Cch / 64, Bsz), 256, 0, stream>>>(query, ws);
    k_sim<<<6, 256, 0, stream>>>(ws);
    k_final<<<(Bsz * Ssz + 2378 + 255) / 256, 256, 0, stream>>>(weight, ws, out);

    // ---- APA ----
    k_apa_u<<<Bsz, 1024, 0, stream>>>(text, proto, w_q, w_bl, w_k, ws);
    k_score<<<dim3(15, 4, Bsz), 256, 0, stream>>>(kin, ws);
    k_softmax<<<Bsz, 256, 0, stream>>>(ws);
    k_kbar<<<dim3(HID, Bsz), 256, 0, stream>>>(kin, ws);
    k_apa_out<<<Bsz, 1024, 0, stream>>>(w_k, w_proj, b_proj, proto, ws, out);
}

// Round 6
// 209.509 us; speedup vs baseline: 1.3434x; 1.1078x over previous
//
#include <hip/hip_runtime.h>
#include <math.h>

#define EPSF 1e-7f
#define Bsz 2
#define Cch 1024
#define Hh 60
#define Ssz 3600
#define HID 256
#define TDIM 300
#define MH 473

// pool tiling
#define TROWS 15
#define LROWS 21          // TROWS + 6 halo
#define LPITCH 68         // 4-col zero pad both sides of 60 cols
#define CPG 8             // channels per block (processed as 4 float2 pairs)

// workspace layout (float offsets)
#define OFF_SN2    0            // 6*3600  atomic -> zeroed by k_zero
#define OFF_WMAP   21600        // 6*3600  mask-premultiplied pool(1/sn)
#define OFF_V      43200        // 6*1024
#define OFF_U      49344        // 2*256
#define OFF_KBAR   49856        // 2*256
#define OFF_DOTP   50368        // 16 groups * [2][3][3600] partials (non-atomic)
#define OFF_SCOREP 395968       // 4 groups * [2][3600] partials (non-atomic)
#define ZERO_WS    21600        // floats of ws to zero (SN2 only)
#define ZERO_OUT   9578         // corr outputs zeroed (APA region written directly)

// ---------------- zero SN2 + corr output region -----------------------------
__global__ void k_zero(float* __restrict__ ws, float* __restrict__ out) {
    int i = blockIdx.x * 256 + threadIdx.x;
    if (i < ZERO_WS) ws[i] = 0.f;
    else if (i < ZERO_WS + ZERO_OUT) out[i - ZERO_WS] = 0.f;
}

// ---------------- pass A: sn2[b][kt][q] = sum_c pool_kt(supp_c*mask)(q)^2 --
__global__ void __launch_bounds__(256) k_pool_sn2(const float* __restrict__ supp,
                                                  const float* __restrict__ masks,
                                                  float* __restrict__ sn2g) {
    __shared__ float  mk[LROWS * LPITCH];
    __shared__ float2 raw[LROWS * LPITCH];
    __shared__ float2 h5s[LROWS * LPITCH];
    __shared__ float2 h7s[LROWS * LPITCH];
    int tid = threadIdx.x;
    int tile = blockIdx.x;       // 0..3
    int cg = blockIdx.y;         // 0..127
    int b = blockIdx.z;          // 0..1
    int y0 = tile * TROWS;

    const float2 z2 = {0.f, 0.f};
    for (int i = tid; i < LROWS * LPITCH; i += 256) {
        mk[i] = 0.f; raw[i] = z2; h5s[i] = z2; h7s[i] = z2;
    }
    __syncthreads();

    int lr[5], lx[5]; bool lv[5], la[5];
    #pragma unroll
    for (int j = 0; j < 5; ++j) {
        int idx = tid + 256 * j;
        int r = idx / 60, x = idx - 60 * r;
        lr[j] = r; lx[j] = x;
        la[j] = idx < 1260;
        int iy = y0 - 3 + r;
        lv[j] = la[j] && (iy >= 0) && (iy < Hh);
    }
    #pragma unroll
    for (int j = 0; j < 5; ++j)
        if (lv[j]) {
            int iy = y0 - 3 + lr[j];
            mk[lr[j] * LPITCH + 4 + lx[j]] =
                masks[(size_t)b * MH * MH + (size_t)(iy * 8) * MH + lx[j] * 8];
        }

    int orow[4], ox[4]; bool ov[4];
    #pragma unroll
    for (int j = 0; j < 4; ++j) {
        int o = tid + 256 * j;
        int oy = o / 60, x = o - 60 * oy;
        orow[j] = oy + 3; ox[j] = x; ov[j] = o < 900;
    }
    float a0[4] = {0,0,0,0}, a1[4] = {0,0,0,0}, a2[4] = {0,0,0,0};

    const float* chbase = supp + ((size_t)b * Cch + (size_t)cg * CPG) * Ssz + (y0 - 3) * 60;
    float pf0[5], pf1[5];
    #pragma unroll
    for (int j = 0; j < 5; ++j) {
        pf0[j] = lv[j] ? chbase[tid + 256 * j] : 0.f;
        pf1[j] = lv[j] ? chbase[Ssz + tid + 256 * j] : 0.f;
    }

    for (int p = 0; p < CPG / 2; ++p) {
        __syncthreads();
        #pragma unroll
        for (int j = 0; j < 5; ++j)
            if (lv[j]) {
                float m = mk[lr[j] * LPITCH + 4 + lx[j]];
                raw[lr[j] * LPITCH + 4 + lx[j]] = make_float2(pf0[j] * m, pf1[j] * m);
            }
        __syncthreads();
        #pragma unroll
        for (int j = 0; j < 5; ++j)
            if (la[j]) {
                int base = lr[j] * LPITCH + 4 + lx[j];
                float2 m3 = raw[base - 3], m2 = raw[base - 2], m1 = raw[base - 1];
                float2 c0 = raw[base], p1 = raw[base + 1], p2 = raw[base + 2], p3 = raw[base + 3];
                float2 h5, h7;
                h5.x = m2.x + m1.x + c0.x + p1.x + p2.x;
                h5.y = m2.y + m1.y + c0.y + p1.y + p2.y;
                h7.x = h5.x + m3.x + p3.x;
                h7.y = h5.y + m3.y + p3.y;
                h5s[base] = h5; h7s[base] = h7;
            }
        __syncthreads();
        if (p + 1 < CPG / 2) {
            const float* nb = chbase + (size_t)(2 * p + 2) * Ssz;
            #pragma unroll
            for (int j = 0; j < 5; ++j) {
                pf0[j] = lv[j] ? nb[tid + 256 * j] : 0.f;
                pf1[j] = lv[j] ? nb[Ssz + tid + 256 * j] : 0.f;
            }
        }
        #pragma unroll
        for (int j = 0; j < 4; ++j)
            if (ov[j]) {
                int base = orow[j] * LPITCH + 4 + ox[j];
                float2 sa = h5s[base - 2*LPITCH], sb = h5s[base - LPITCH], sc0 = h5s[base];
                float2 sd = h5s[base + LPITCH], se = h5s[base + 2*LPITCH];
                float p55x = (sa.x + sb.x + sc0.x + sd.x + se.x) * (1.f / 25.f);
                float p55y = (sa.y + sb.y + sc0.y + sd.y + se.y) * (1.f / 25.f);
                float2 ra = raw[base - 3*LPITCH], rb = raw[base - 2*LPITCH], rc = raw[base - LPITCH];
                float2 rd = raw[base], re = raw[base + LPITCH], rf = raw[base + 2*LPITCH], rg = raw[base + 3*LPITCH];
                float p71x = (ra.x + rb.x + rc.x + rd.x + re.x + rf.x + rg.x) * (1.f / 7.f);
                float p71y = (ra.y + rb.y + rc.y + rd.y + re.y + rf.y + rg.y) * (1.f / 7.f);
                float2 h7v = h7s[base];
                float p17x = h7v.x * (1.f / 7.f), p17y = h7v.y * (1.f / 7.f);
                a0[j] += p55x * p55x + p55y * p55y;
                a1[j] += p71x * p71x + p71y * p71y;
                a2[j] += p17x * p17x + p17y * p17y;
            }
    }
    float* g0 = sn2g + ((size_t)b * 3 + 0) * Ssz;
    float* g1 = sn2g + ((size_t)b * 3 + 1) * Ssz;
    float* g2 = sn2g + ((size_t)b * 3 + 2) * Ssz;
    #pragma unroll
    for (int j = 0; j < 4; ++j)
        if (ov[j]) {
            int q = (y0 + orow[j] - 3) * 60 + ox[j];
            atomicAdd(&g0[q], a0[j]);
            atomicAdd(&g1[q], a1[j]);
            atomicAdd(&g2[q], a2[j]);
        }
}

// ---------------- wm[b][kt] = mask * pool_kt(1/sn), row-tiled ---------------
__global__ void k_wmap(const float* __restrict__ sn2g, const float* __restrict__ masks,
                       float* __restrict__ wmapg) {
    __shared__ float inv[LROWS * LPITCH];
    int tile = blockIdx.x;       // 0..3
    int bk = blockIdx.y;         // 0..5 = b*3+kt
    int b = bk / 3, kt = bk % 3;
    int tid = threadIdx.x;
    int y0 = tile * TROWS;
    for (int i = tid; i < LROWS * LPITCH; i += 256) inv[i] = 0.f;
    __syncthreads();
    const float* sn2 = sn2g + (size_t)bk * Ssz;
    #pragma unroll
    for (int j = 0; j < 5; ++j) {
        int idx = tid + 256 * j;
        if (idx < 1260) {
            int r = idx / 60, x = idx - 60 * r;
            int iy = y0 - 3 + r;
            if (iy >= 0 && iy < Hh)
                inv[r * LPITCH + 4 + x] = 1.0f / sqrtf(fmaxf(sn2[iy * 60 + x], 1e-30f));
        }
    }
    __syncthreads();
    int kh = (kt == 0) ? 5 : (kt == 1) ? 7 : 1;
    int kw = (kt == 0) ? 5 : (kt == 2) ? 7 : 1;
    int rh = kh / 2, rw = kw / 2;
    float norm = 1.f / (float)(kh * kw);
    #pragma unroll
    for (int j = 0; j < 4; ++j) {
        int o = tid + 256 * j;
        if (o < 900) {
            int oy = o / 60, x = o - 60 * oy;
            int base = (oy + 3) * LPITCH + 4 + x;
            float s = 0.f;
            for (int dy = -rh; dy <= rh; ++dy)
                for (int dx = -rw; dx <= rw; ++dx)
                    s += inv[base + dy * LPITCH + dx];
            int gy = y0 + oy;
            float m = masks[(size_t)b * MH * MH + (size_t)(gy * 8) * MH + x * 8];
            wmapg[(size_t)bk * Ssz + gy * 60 + x] = s * norm * m;
        }
    }
}

// ---------------- v[b][kt][c] = sum_q supp[c,q]*wm[kt][q] (float4) ----------
__global__ void k_v(const float* __restrict__ supp, float* __restrict__ ws) {
    int c = blockIdx.x, b = blockIdx.y;
    int tid = threadIdx.x;
    int lane = tid & 63, w = tid >> 6;
    const float4* sp4 = (const float4*)(supp + ((size_t)b * Cch + c) * Ssz);
    const float4* w04 = (const float4*)(ws + OFF_WMAP + (size_t)(b * 3 + 0) * Ssz);
    const float4* w14 = (const float4*)(ws + OFF_WMAP + (size_t)(b * 3 + 1) * Ssz);
    const float4* w24 = (const float4*)(ws + OFF_WMAP + (size_t)(b * 3 + 2) * Ssz);
    float a0 = 0, a1 = 0, a2 = 0;
    #pragma unroll
    for (int j = 0; j < 4; ++j) {
        int idx = tid + 256 * j;
        if (idx < 900) {
            float4 f = sp4[idx];
            float4 g0 = w04[idx], g1 = w14[idx], g2 = w24[idx];
            a0 += f.x * g0.x + f.y * g0.y + f.z * g0.z + f.w * g0.w;
            a1 += f.x * g1.x + f.y * g1.y + f.z * g1.z + f.w * g1.w;
            a2 += f.x * g2.x + f.y * g2.y + f.z * g2.z + f.w * g2.w;
        }
    }
    #pragma unroll
    for (int m = 32; m >= 1; m >>= 1) {
        a0 += __shfl_xor(a0, m, 64);
        a1 += __shfl_xor(a1, m, 64);
        a2 += __shfl_xor(a2, m, 64);
    }
    __shared__ float r[3][4];
    if (lane == 0) { r[0][w] = a0; r[1][w] = a1; r[2][w] = a2; }
    __syncthreads();
    if (tid < 3) {
        float s = r[tid][0] + r[tid][1] + r[tid][2] + r[tid][3];
        ws[OFF_V + (size_t)(b * 3 + tid) * Cch + c] = s;
    }
}

// ---------------- dotp[cc][b][kt][q] = sum_{c in cc} query[c,q]*v[kt][c] ----
__global__ void k_dot(const float* __restrict__ query, float* __restrict__ ws) {
    int qt = blockIdx.x, cc = blockIdx.y, b = blockIdx.z;
    int q = qt * 256 + threadIdx.x;
    if (q >= Ssz) return;
    const float* v0 = ws + OFF_V + (size_t)(b * 3 + 0) * Cch;
    const float* v1 = ws + OFF_V + (size_t)(b * 3 + 1) * Cch;
    const float* v2 = ws + OFF_V + (size_t)(b * 3 + 2) * Cch;
    float a0 = 0, a1 = 0, a2 = 0;
    int c0 = cc * 64;
    #pragma unroll 8
    for (int c = c0; c < c0 + 64; ++c) {
        float qv = query[((size_t)b * Cch + c) * Ssz + q];
        a0 += qv * v0[c]; a1 += qv * v1[c]; a2 += qv * v2[c];
    }
    float* dst = ws + OFF_DOTP + (size_t)((cc * 2 + b) * 3) * Ssz + q;
    dst[0] = a0; dst[Ssz] = a1; dst[2 * Ssz] = a2;
}

// ---------------- sim: sum partials, pool, minmax-norm, write outputs -------
// one block per (b,kt); 1024 threads; fuses old k_sim + k_final (linearity).
__global__ void __launch_bounds__(1024) k_sim(const float* __restrict__ weight,
                                              float* __restrict__ ws,
                                              float* __restrict__ out) {
    __shared__ float dpad[66 * LPITCH];
    __shared__ float hbuf[66 * LPITCH];
    __shared__ float rmin[16], rmax[16];
    int bk = blockIdx.x; int b = bk / 3; int kt = bk % 3;
    int tid = threadIdx.x;
    int lane = tid & 63, w = tid >> 6;

    // stage dotmap = sum of 16 partials
    const float* dp0 = ws + OFF_DOTP + (size_t)(b * 3 + kt) * Ssz;
    for (int i = tid; i < 66 * LPITCH; i += 1024) {
        int r = i / LPITCH, col = i - r * LPITCH;
        int y = r - 3, x = col - 4;
        float s = 0.f;
        if (y >= 0 && y < Hh && x >= 0 && x < Hh) {
            int q = y * Hh + x;
            #pragma unroll
            for (int g = 0; g < 16; ++g) s += dp0[(size_t)g * 6 * Ssz + q];
        }
        dpad[i] = s;
    }
    __syncthreads();
    // separable horizontal stage (only what this kt needs)
    if (kt != 1) {
        for (int idx = tid; idx < 66 * 60; idx += 1024) {
            int r = idx / 60, x = idx - 60 * r;
            int base = r * LPITCH + 4 + x;
            if (kt == 0) {
                hbuf[base] = dpad[base - 2] + dpad[base - 1] + dpad[base]
                           + dpad[base + 1] + dpad[base + 2];
            } else {
                hbuf[base] = dpad[base - 3] + dpad[base - 2] + dpad[base - 1] + dpad[base]
                           + dpad[base + 1] + dpad[base + 2] + dpad[base + 3];
            }
        }
    }
    __syncthreads();
    float norm = ((kt == 0) ? (1.f / 25.f) : (1.f / 7.f)) * (1.f / (float)Ssz);
    float vals[4];
    float vmin = INFINITY, vmax = -INFINITY;
    #pragma unroll
    for (int j = 0; j < 4; ++j) {
        int q = tid + j * 1024;
        if (q < Ssz) {
            int y = q / Hh, x = q - y * Hh;
            int base = (y + 3) * LPITCH + 4 + x;
            float s;
            if (kt == 0)
                s = hbuf[base - 2*LPITCH] + hbuf[base - LPITCH] + hbuf[base]
                  + hbuf[base + LPITCH] + hbuf[base + 2*LPITCH];
            else if (kt == 1)
                s = dpad[base - 3*LPITCH] + dpad[base - 2*LPITCH] + dpad[base - LPITCH]
                  + dpad[base] + dpad[base + LPITCH] + dpad[base + 2*LPITCH] + dpad[base + 3*LPITCH];
            else
                s = hbuf[base];
            float val = s * norm;
            vals[j] = val;
            vmin = fminf(vmin, val); vmax = fmaxf(vmax, val);
        }
    }
    // block min/max reduce: wave shuffle + 16-wave LDS
    #pragma unroll
    for (int m = 32; m >= 1; m >>= 1) {
        vmin = fminf(vmin, __shfl_xor(vmin, m, 64));
        vmax = fmaxf(vmax, __shfl_xor(vmax, m, 64));
    }
    if (lane == 0) { rmin[w] = vmin; rmax[w] = vmax; }
    __syncthreads();
    float mn = rmin[0], mx = rmax[0];
    #pragma unroll
    for (int ww = 1; ww < 16; ++ww) {
        mn = fminf(mn, rmin[ww]); mx = fmaxf(mx, rmax[ww]);
    }
    float inv = 1.f / (mx - mn + EPSF);
    float wq3 = weight[b] * (1.f / 3.f);
    // corr1 contribution + stash normalized vals in hbuf (as flat [3600])
    __syncthreads();   // everyone done reading hbuf/dpad for window sums
    #pragma unroll
    for (int j = 0; j < 4; ++j) {
        int q = tid + j * 1024;
        if (q < Ssz) {
            float vn = (vals[j] - mn) * inv;
            atomicAdd(&out[b * Ssz + q], wq3 * vn);
            hbuf[q] = vn;
        }
    }
    __syncthreads();
    // downsampled contributions (bilinear is linear in its input)
    #pragma unroll
    for (int j = 0; j < 2; ++j) {
        int o = tid + j * 1024;
        if (o >= 1189) continue;
        int O, p, outi;
        if (o < 900)       { O = 30; p = o;        outi = 7200 + b * 900 + p; }
        else if (o < 1125) { O = 15; p = o - 900;  outi = 9000 + b * 225 + p; }
        else               { O = 8;  p = o - 1125; outi = 9450 + b * 64 + p; }
        int y = p / O, x = p - y * O;
        float sc = 59.f / (float)(O - 1);
        float py = y * sc, px = x * sc;
        int y0 = (int)floorf(py), x0 = (int)floorf(px);
        int y1 = min(y0 + 1, 59), x1 = min(x0 + 1, 59);
        float wy = py - y0, wx = px - x0;
        float v = hbuf[y0 * 60 + x0] * (1.f - wy) * (1.f - wx)
                + hbuf[y1 * 60 + x0] * wy * (1.f - wx)
                + hbuf[y0 * 60 + x1] * (1.f - wy) * wx
                + hbuf[y1 * 60 + x1] * wy * wx;
        atomicAdd(&out[outi], wq3 * v);
    }
}

// ---------------- APA: u = w_k^T (w_bl^T (w_q^T [text;proto])) --------------
__global__ void __launch_bounds__(1024, 1)
k_apa_u(const float* __restrict__ text, const float* __restrict__ proto,
        const float* __restrict__ w_q, const float* __restrict__ w_bl,
        const float* __restrict__ w_k, float* __restrict__ ws) {
    int b = blockIdx.x;
    int tid = threadIdx.x;
    int lane = tid & 63, w = tid >> 6;        // w = 0..15
    __shared__ float4 p4[16][64];
    __shared__ float qxs[256], qws[256];
    const float4* wq4 = (const float4*)w_q;
    const float4* wbl4 = (const float4*)w_bl;
    const float4* wk4 = (const float4*)w_k;

    float4 acc = {0.f, 0.f, 0.f, 0.f};
    #pragma unroll
    for (int j = 0; j < 35; ++j) {
        int e = w + 16 * j;
        if (e < TDIM + HID) {
            float x = (e < TDIM) ? text[b * TDIM + e] : proto[b * HID + e - TDIM];
            float4 f = wq4[(size_t)e * 64 + lane];
            acc.x += x * f.x; acc.y += x * f.y; acc.z += x * f.z; acc.w += x * f.w;
        }
    }
    p4[w][lane] = acc;
    __syncthreads();
    if (tid < 256) {
        const float* pf = (const float*)p4;
        float s = 0.f;
        #pragma unroll
        for (int ww = 0; ww < 16; ++ww) s += pf[ww * 256 + tid];
        qxs[tid] = s;
    }
    __syncthreads();

    acc.x = acc.y = acc.z = acc.w = 0.f;
    #pragma unroll
    for (int j = 0; j < 16; ++j) {
        int e = w + 16 * j;
        float x = qxs[e];
        float4 f = wbl4[(size_t)e * 64 + lane];
        acc.x += x * f.x; acc.y += x * f.y; acc.z += x * f.z; acc.w += x * f.w;
    }
    p4[w][lane] = acc;
    __syncthreads();
    if (tid < 256) {
        const float* pf = (const float*)p4;
        float s = 0.f;
        #pragma unroll
        for (int ww = 0; ww < 16; ++ww) s += pf[ww * 256 + tid];
        qws[tid] = s;
    }
    __syncthreads();

    acc.x = acc.y = acc.z = acc.w = 0.f;
    #pragma unroll
    for (int j = 0; j < 16; ++j) {
        int e = w + 16 * j;
        float x = qws[e];
        float4 f = wk4[(size_t)e * 64 + lane];
        acc.x += x * f.x; acc.y += x * f.y; acc.z += x * f.z; acc.w += x * f.w;
    }
    p4[w][lane] = acc;
    __syncthreads();
    if (tid < 256) {
        const float* pf = (const float*)p4;
        float s = 0.f;
        #pragma unroll
        for (int ww = 0; ww < 16; ++ww) s += pf[ww * 256 + tid];
        ws[OFF_U + b * HID + tid] = s;
    }
}

// ---------------- scorep[g][b][s] = sum_{i in g} u[i]*k[b,i,s] --------------
__global__ void k_score(const float* __restrict__ kin, float* __restrict__ ws) {
    int st = blockIdx.x, g = blockIdx.y, b = blockIdx.z;
    int s = st * 256 + threadIdx.x;
    if (s >= Ssz) return;
    const float* u = ws + OFF_U + b * HID;
    float acc = 0.f;
    int i0 = g * 64;
    #pragma unroll 8
    for (int i = i0; i < i0 + 64; ++i)
        acc += u[i] * kin[((size_t)b * HID + i) * Ssz + s];
    ws[OFF_SCOREP + (size_t)(g * 2 + b) * Ssz + s] = acc;
}

// ---------------- kbar[b,i] = softmax(score) . k[b,i,:]  (softmax fused) ----
__global__ void k_kbar(const float* __restrict__ kin, float* __restrict__ ws) {
    int i = blockIdx.x, b = blockIdx.y;
    int tid = threadIdx.x;
    int lane = tid & 63, w = tid >> 6;
    __shared__ float r1[4], r2[4];
    const float4* s0 = (const float4*)(ws + OFF_SCOREP + (size_t)(0 * 2 + b) * Ssz);
    const float4* s1 = (const float4*)(ws + OFF_SCOREP + (size_t)(1 * 2 + b) * Ssz);
    const float4* s2 = (const float4*)(ws + OFF_SCOREP + (size_t)(2 * 2 + b) * Ssz);
    const float4* s3 = (const float4*)(ws + OFF_SCOREP + (size_t)(3 * 2 + b) * Ssz);
    float4 sv[4]; bool act[4];
    float mx = -INFINITY;
    #pragma unroll
    for (int j = 0; j < 4; ++j) {
        int idx = tid + 256 * j;
        act[j] = idx < 900;
        if (act[j]) {
            float4 a = s0[idx], c = s1[idx], d = s2[idx], e = s3[idx];
            float4 v;
            v.x = a.x + c.x + d.x + e.x;
            v.y = a.y + c.y + d.y + e.y;
            v.z = a.z + c.z + d.z + e.z;
            v.w = a.w + c.w + d.w + e.w;
            sv[j] = v;
            mx = fmaxf(mx, fmaxf(fmaxf(v.x, v.y), fmaxf(v.z, v.w)));
        }
    }
    #pragma unroll
    for (int m = 32; m >= 1; m >>= 1) mx = fmaxf(mx, __shfl_xor(mx, m, 64));
    if (lane == 0) r1[w] = mx;
    __syncthreads();
    mx = fmaxf(fmaxf(r1[0], r1[1]), fmaxf(r1[2], r1[3]));
    __syncthreads();
    // exp + sum + weighted sum with kin row
    const float4* kr = (const float4*)(kin + ((size_t)b * HID + i) * Ssz);
    float se = 0.f, wsum = 0.f;
    #pragma unroll
    for (int j = 0; j < 4; ++j) {
        if (act[j]) {
            int idx = tid + 256 * j;
            float4 v = sv[j];
            float ex = expf(v.x - mx), ey = expf(v.y - mx);
            float ez = expf(v.z - mx), ew = expf(v.w - mx);
            se += ex + ey + ez + ew;
            float4 k4 = kr[idx];
            wsum += ex * k4.x + ey * k4.y + ez * k4.z + ew * k4.w;
        }
    }
    #pragma unroll
    for (int m = 32; m >= 1; m >>= 1) {
        se += __shfl_xor(se, m, 64);
        wsum += __shfl_xor(wsum, m, 64);
    }
    if (lane == 0) { r1[w] = se; r2[w] = wsum; }
    __syncthreads();
    if (tid == 0) {
        float seT = r1[0] + r1[1] + r1[2] + r1[3];
        float wsT = r2[0] + r2[1] + r2[2] + r2[3];
        ws[OFF_KBAR + b * HID + i] = wsT / seT;
    }
}

// ---------------- out = w_proj^T (w_k kbar) + b + proto ---------------------
__global__ void __launch_bounds__(1024, 1)
k_apa_out(const float* __restrict__ w_k, const float* __restrict__ w_proj,
          const float* __restrict__ b_proj, const float* __restrict__ proto,
          const float* __restrict__ ws, float* __restrict__ out) {
    int b = blockIdx.x;
    int tid = threadIdx.x;
    int lane = tid & 63, w = tid >> 6;
    __shared__ float4 kbs[64];
    __shared__ float o1s[256];
    __shared__ float4 p4[16][64];
    const float4* wk4 = (const float4*)w_k;
    const float4* wp4 = (const float4*)w_proj;

    if (tid < 64) kbs[tid] = ((const float4*)(ws + OFF_KBAR + b * HID))[tid];
    __syncthreads();

    float4 kb4 = kbs[lane];
    #pragma unroll
    for (int r = 0; r < 16; ++r) {
        int h = w + 16 * r;
        float4 f = wk4[(size_t)h * 64 + lane];
        float p = f.x * kb4.x + f.y * kb4.y + f.z * kb4.z + f.w * kb4.w;
        #pragma unroll
        for (int m = 32; m >= 1; m >>= 1) p += __shfl_xor(p, m, 64);
        if (lane == 0) o1s[h] = p;
    }
    __syncthreads();

    float4 acc = {0.f, 0.f, 0.f, 0.f};
    #pragma unroll
    for (int j = 0; j < 16; ++j) {
        int d = w + 16 * j;
        float x = o1s[d];
        float4 f = wp4[(size_t)d * 64 + lane];
        acc.x += x * f.x; acc.y += x * f.y; acc.z += x * f.z; acc.w += x * f.w;
    }
    p4[w][lane] = acc;
    __syncthreads();
    if (tid < 256) {
        const float* pf = (const float*)p4;
        float s = 0.f;
        #pragma unroll
        for (int ww = 0; ww < 16; ++ww) s += pf[ww * 256 + tid];
        out[9578 + b * HID + tid] = s + b_proj[tid] + proto[b * HID + tid];
    }
}

extern "C" void kernel_launch(void* const* d_in, const int* in_sizes, int n_in,
                              void* d_out, int out_size, void* d_ws, size_t ws_size,
                              hipStream_t stream) {
    const float* weight = (const float*)d_in[0];
    const float* query  = (const float*)d_in[1];
    const float* supp   = (const float*)d_in[2];
    const float* masks  = (const float*)d_in[3];
    const float* kin    = (const float*)d_in[4];
    const float* text   = (const float*)d_in[5];
    const float* proto  = (const float*)d_in[6];
    const float* w_q    = (const float*)d_in[7];
    const float* w_k    = (const float*)d_in[8];
    const float* w_bl   = (const float*)d_in[9];
    const float* w_proj = (const float*)d_in[10];
    const float* b_proj = (const float*)d_in[11];
    float* out = (float*)d_out;
    float* ws  = (float*)d_ws;

    k_zero<<<(ZERO_WS + ZERO_OUT + 255) / 256, 256, 0, stream>>>(ws, out);

    // ---- SPM ----
    k_pool_sn2<<<dim3(4, Cch / CPG, Bsz), 256, 0, stream>>>(supp, masks, ws + OFF_SN2);
    k_wmap<<<dim3(4, 6), 256, 0, stream>>>(ws + OFF_SN2, masks, ws + OFF_WMAP);
    k_v<<<dim3(Cch, Bsz), 256, 0, stream>>>(supp, ws);
    k_dot<<<dim3(15, 16, Bsz), 256, 0, stream>>>(query, ws);
    k_sim<<<6, 1024, 0, stream>>>(weight, ws, out);

    // ---- APA ----
    k_apa_u<<<Bsz, 1024, 0, stream>>>(text, proto, w_q, w_bl, w_k, ws);
    k_score<<<dim3(15, 4, Bsz), 256, 0, stream>>>(kin, ws);
    k_kbar<<<dim3(HID, Bsz), 256, 0, stream>>>(kin, ws);
    k_apa_out<<<Bsz, 1024, 0, stream>>>(w_k, w_proj, b_proj, proto, ws, out);
}